// Round 1
// baseline (418.814 us; speedup 1.0000x reference)
//
#include <hip/hip_runtime.h>
#include <stdint.h>

#define B_ 16
#define C_ 512
#define N_ 4096

typedef float f32x4 __attribute__((ext_vector_type(4)));
typedef __bf16 bf16x8 __attribute__((ext_vector_type(8)));

// fp32 -> bf16 round-to-nearest-even (inputs are finite normals; no NaN path needed)
static __device__ __forceinline__ unsigned short f2bf(float f) {
    unsigned int u = __float_as_uint(f);
    u += 0x7fffu + ((u >> 16) & 1u);
    return (unsigned short)(u >> 16);
}

// async global->LDS, 16B per lane (global_load_lds_dwordx4)
static __device__ __forceinline__ void gload_lds16(const void* g, void* l) {
    __builtin_amdgcn_global_load_lds(
        (__attribute__((address_space(1))) unsigned int*)(g),
        (__attribute__((address_space(3))) unsigned int*)(l),
        16, 0, 0);
}

// ---------------------------------------------------------------------------
// Kernel 1: x (fp32, BxCxN) -> q16 (bf16, BxCxN) and qt16 (bf16, BxNxC)
// 64x64 tiles through LDS for the transpose; q16 written straight through.
// ---------------------------------------------------------------------------
__global__ __launch_bounds__(256)
void convert_transpose(const float* __restrict__ x,
                       unsigned short* __restrict__ q16,
                       unsigned short* __restrict__ qt16) {
    __shared__ unsigned short tile[64][72];   // [c][n], +8 pad breaks transpose conflicts
    int b  = blockIdx.z;
    int c0 = blockIdx.y * 64, n0 = blockIdx.x * 64;
    int tx = threadIdx.x & 15, ty = threadIdx.x >> 4;

    const float*    xb  = x    + ((size_t)b * C_ + c0) * N_ + n0;
    unsigned short* qb  = q16  + ((size_t)b * C_ + c0) * N_ + n0;
    unsigned short* qtb = qt16 + ((size_t)b * N_ + n0) * C_ + c0;

#pragma unroll
    for (int s = 0; s < 4; ++s) {
        int rr = s * 16 + ty;
        float4 v = *(const float4*)(xb + (size_t)rr * N_ + tx * 4);
        unsigned short h0 = f2bf(v.x), h1 = f2bf(v.y), h2 = f2bf(v.z), h3 = f2bf(v.w);
        tile[rr][tx * 4 + 0] = h0;
        tile[rr][tx * 4 + 1] = h1;
        tile[rr][tx * 4 + 2] = h2;
        tile[rr][tx * 4 + 3] = h3;
        ushort4 p; p.x = h0; p.y = h1; p.z = h2; p.w = h3;
        *(ushort4*)(qb + (size_t)rr * N_ + tx * 4) = p;
    }
    __syncthreads();
#pragma unroll
    for (int s = 0; s < 4; ++s) {
        int nr = s * 16 + ty;
        ushort4 p;
        p.x = tile[tx * 4 + 0][nr];
        p.y = tile[tx * 4 + 1][nr];
        p.z = tile[tx * 4 + 2][nr];
        p.w = tile[tx * 4 + 3][nr];
        *(ushort4*)(qtb + (size_t)nr * C_ + tx * 4) = p;
    }
}

// ---------------------------------------------------------------------------
// Kernel 2: energy[b] = Q[b] . Q[b]^T   (M=N=512, K=4096, bf16 MFMA)
// m97 structure: 128x128 tile, BK=32, global_load_lds width 16, 4 waves 2x2,
// each wave 4x4 of 16x16x32 MFMA.
// ---------------------------------------------------------------------------
template<int K>
__global__ __launch_bounds__(256)
void gemm_bt_energy(const unsigned short* __restrict__ q16,
                    float* __restrict__ energy) {
    int b = blockIdx.z;
    const unsigned short* Ab = q16 + (size_t)b * C_ * K;
    const unsigned short* Bb = Ab;                       // Gram: B operand = A operand
    int m0 = blockIdx.y * 128, n0 = blockIdx.x * 128;

    __shared__ unsigned short As[128 * 32];
    __shared__ unsigned short Bs[128 * 32];

    int t = threadIdx.x;
    int lane = t & 63, wave = t >> 6;
    int wm = (wave >> 1) * 64, wn = (wave & 1) * 64;
    int qd = lane >> 4, r = lane & 15;

    f32x4 acc[4][4] = {};

    for (int k0 = 0; k0 < K; k0 += 32) {
        __syncthreads();
#pragma unroll
        for (int i = 0; i < 2; ++i) {
            int o = (i * 256 + t) * 16;          // LDS byte offset, 0..8191
            int mrow = o >> 6, inrow = o & 63;   // 64 B per 32-elem bf16 row
            gload_lds16((const char*)Ab + (size_t)(m0 + mrow) * (K * 2) + k0 * 2 + inrow,
                        (char*)As + o);
            gload_lds16((const char*)Bb + (size_t)(n0 + mrow) * (K * 2) + k0 * 2 + inrow,
                        (char*)Bs + o);
        }
        __syncthreads();

        bf16x8 af[4], bfr[4];
#pragma unroll
        for (int i = 0; i < 4; ++i)
            af[i] = *(const bf16x8*)&As[(wm + i * 16 + r) * 32 + qd * 8];
#pragma unroll
        for (int j = 0; j < 4; ++j)
            bfr[j] = *(const bf16x8*)&Bs[(wn + j * 16 + r) * 32 + qd * 8];
#pragma unroll
        for (int i = 0; i < 4; ++i)
#pragma unroll
            for (int j = 0; j < 4; ++j)
                acc[i][j] = __builtin_amdgcn_mfma_f32_16x16x32_bf16(af[i], bfr[j], acc[i][j], 0, 0, 0);
    }

    float* Db = energy + (size_t)b * C_ * C_;
#pragma unroll
    for (int i = 0; i < 4; ++i)
#pragma unroll
        for (int j = 0; j < 4; ++j) {
            int row = m0 + wm + i * 16 + qd * 4;
            int col = n0 + wn + j * 16 + r;
#pragma unroll
            for (int rr = 0; rr < 4; ++rr)
                Db[(size_t)(row + rr) * C_ + col] = acc[i][j][rr];
        }
}

// ---------------------------------------------------------------------------
// Kernel 3: attention = softmax(max - energy) = softmax(-energy), row-wise.
// One block per (b,c) row of 512; output bf16.
// ---------------------------------------------------------------------------
__global__ __launch_bounds__(256)
void softmax_neg(const float* __restrict__ energy, unsigned short* __restrict__ att) {
    size_t row = blockIdx.x;
    const float* e = energy + row * C_;
    int t = threadIdx.x;

    float e0 = e[t], e1 = e[t + 256];
    float m = fminf(e0, e1);                 // min(e) == -max(-e)
#pragma unroll
    for (int off = 32; off > 0; off >>= 1) m = fminf(m, __shfl_down(m, off, 64));
    __shared__ float red[8];
    if ((t & 63) == 0) red[t >> 6] = m;
    __syncthreads();
    m = fminf(fminf(red[0], red[1]), fminf(red[2], red[3]));

    float p0 = __expf(m - e0), p1 = __expf(m - e1);   // exp(-e - max(-e)) in [0,1]
    float s = p0 + p1;
#pragma unroll
    for (int off = 32; off > 0; off >>= 1) s += __shfl_down(s, off, 64);
    if ((t & 63) == 0) red[4 + (t >> 6)] = s;
    __syncthreads();
    s = red[4] + red[5] + red[6] + red[7];
    float inv = 1.0f / s;

    att[row * C_ + t]       = f2bf(p0 * inv);
    att[row * C_ + t + 256] = f2bf(p1 * inv);
}

// ---------------------------------------------------------------------------
// Kernel 4: y[b] = gamma * (attention[b] . Q[b]) + x[b]
// A = att (512x512 bf16), B = Qt (4096x512 bf16, row n holds Q[:,n]) -> bt GEMM,
// K=512. Fused epilogue reads x, writes y.
// ---------------------------------------------------------------------------
__global__ __launch_bounds__(256)
void gemm_bt_out(const unsigned short* __restrict__ att,
                 const unsigned short* __restrict__ qt16,
                 const float* __restrict__ x,
                 const float* __restrict__ gamma,
                 float* __restrict__ y) {
    const int K = 512;
    int b = blockIdx.z;
    const unsigned short* Ab = att  + (size_t)b * C_ * K;
    const unsigned short* Bb = qt16 + (size_t)b * N_ * K;
    int m0 = blockIdx.y * 128;    // c
    int n0 = blockIdx.x * 128;    // n (spatial)

    __shared__ unsigned short As[128 * 32];
    __shared__ unsigned short Bs[128 * 32];

    int t = threadIdx.x;
    int lane = t & 63, wave = t >> 6;
    int wm = (wave >> 1) * 64, wn = (wave & 1) * 64;
    int qd = lane >> 4, r = lane & 15;

    f32x4 acc[4][4] = {};

    for (int k0 = 0; k0 < K; k0 += 32) {
        __syncthreads();
#pragma unroll
        for (int i = 0; i < 2; ++i) {
            int o = (i * 256 + t) * 16;
            int mrow = o >> 6, inrow = o & 63;
            gload_lds16((const char*)Ab + (size_t)(m0 + mrow) * (K * 2) + k0 * 2 + inrow,
                        (char*)As + o);
            gload_lds16((const char*)Bb + (size_t)(n0 + mrow) * (K * 2) + k0 * 2 + inrow,
                        (char*)Bs + o);
        }
        __syncthreads();

        bf16x8 af[4], bfr[4];
#pragma unroll
        for (int i = 0; i < 4; ++i)
            af[i] = *(const bf16x8*)&As[(wm + i * 16 + r) * 32 + qd * 8];
#pragma unroll
        for (int j = 0; j < 4; ++j)
            bfr[j] = *(const bf16x8*)&Bs[(wn + j * 16 + r) * 32 + qd * 8];
#pragma unroll
        for (int i = 0; i < 4; ++i)
#pragma unroll
            for (int j = 0; j < 4; ++j)
                acc[i][j] = __builtin_amdgcn_mfma_f32_16x16x32_bf16(af[i], bfr[j], acc[i][j], 0, 0, 0);
    }

    float g = gamma[0];
    const float* xb = x + (size_t)b * C_ * N_;
    float*       yb = y + (size_t)b * C_ * N_;
#pragma unroll
    for (int i = 0; i < 4; ++i)
#pragma unroll
        for (int j = 0; j < 4; ++j) {
            int row = m0 + wm + i * 16 + qd * 4;
            int col = n0 + wn + j * 16 + r;
#pragma unroll
            for (int rr = 0; rr < 4; ++rr) {
                size_t idx = (size_t)(row + rr) * N_ + col;
                yb[idx] = g * acc[i][j][rr] + xb[idx];
            }
        }
}

// ---------------------------------------------------------------------------
// Workspace layout (bytes):
//   q16   @ 0          : 16*512*4096*2 = 67,108,864
//   qt16  @ 67108864   : 67,108,864
//   att16 @ 134217728  :  8,388,608
//   energy@ 142606336  : 16,777,216      -> total 159,383,552
// ---------------------------------------------------------------------------
extern "C" void kernel_launch(void* const* d_in, const int* in_sizes, int n_in,
                              void* d_out, int out_size, void* d_ws, size_t ws_size,
                              hipStream_t stream) {
    const float* x     = (const float*)d_in[0];
    const float* gamma = (const float*)d_in[1];
    float*       y     = (float*)d_out;

    char* ws = (char*)d_ws;
    unsigned short* q16   = (unsigned short*)(ws);
    unsigned short* qt16  = (unsigned short*)(ws + 67108864);
    unsigned short* att16 = (unsigned short*)(ws + 134217728);
    float*          energy= (float*)(ws + 142606336);

    convert_transpose<<<dim3(N_ / 64, C_ / 64, B_), dim3(256), 0, stream>>>(x, q16, qt16);
    gemm_bt_energy<N_><<<dim3(C_ / 128, C_ / 128, B_), dim3(256), 0, stream>>>(q16, energy);
    softmax_neg<<<dim3(B_ * C_), dim3(256), 0, stream>>>(energy, att16);
    gemm_bt_out<<<dim3(N_ / 128, C_ / 128, B_), dim3(256), 0, stream>>>(att16, qt16, x, gamma, y);
}